// Round 5
// baseline (805.625 us; speedup 1.0000x reference)
//
#include <hip/hip_runtime.h>
#include <math.h>

// Problem constants (from reference)
#define N_NODES 50000
#define N_EDGES 800000
#define IN_DIM  192      // 2*O + ED
#define BN_EPS  1e-5f

// Workspace layout (4-byte word offsets):
//   P1p    [N,64]  uint @ 0          packed bf16x2 {chan n, chan n+64} of n_feat@W1^T
//   P2p    [N,64]  uint @ 3,200,000  same for W2^T
//   agg    [N,64]  f32  @ 6,400,000
//   stats1 [256]   f32  @ 9,600,000  (sum[128], sumsq[128])
//   ss1    [256]   f32  @ +256       (scale[128], shift[128])
//   stats2 [128]   f32  @ +512
//   ss2    [128]   f32  @ +640
//   hbuf   [E,64]  uint @ 9,601,024  packed bf16x2 {filt,core} at SORTED slot
//   rank   [E]     uint @ OFF_RANK   slot index of edge e in dst-sorted order
//   offs   [N+1]   uint @ OFF_OFFS   CSR row offsets per dst node
//   deg    [N]     uint @ OFF_DEG    histogram scratch
//   cursor [N]     uint @ OFF_CURS   scatter cursors (copy of offs)
//   bsum   [256]   uint @ OFF_BSUM   per-block sums for hierarchical scan
#define OFF_P2P    3200000
#define OFF_AGG    6400000
#define OFF_STATS1 9600000
#define OFF_HBUF   9601024
#define WS_WORDS_NEEDED (OFF_HBUF + (size_t)N_EDGES * 64)
#define OFF_RANK   (OFF_HBUF + (size_t)N_EDGES * 64)
#define OFF_OFFS   (OFF_RANK + N_EDGES)
#define OFF_DEG    (OFF_OFFS + N_NODES + 1)
#define OFF_CURS   (OFF_DEG + N_NODES)
#define OFF_BSUM   (OFF_CURS + N_NODES)
#define WS_WORDS_SORTED (OFF_BSUM + 256)

#define NSCAN_BLOCKS 196   // ceil(50000/256)

typedef __bf16 bf16x8 __attribute__((ext_vector_type(8)));
typedef __bf16 bf16x2 __attribute__((ext_vector_type(2)));
typedef float  f32x4  __attribute__((ext_vector_type(4)));

__device__ __forceinline__ unsigned pack_bf16x2(float lo, float hi) {
  union { bf16x2 v; unsigned u; } pk;
  pk.v[0] = (__bf16)lo; pk.v[1] = (__bf16)hi;
  return pk.u;
}
// fast transcendentals (native v_exp/v_log/v_rcp)
__device__ __forceinline__ float fast_sigmoid(float f) {
  return __builtin_amdgcn_rcpf(1.f + __expf(-f));
}
__device__ __forceinline__ float fast_softplus(float g) {
  return fmaxf(g, 0.f) + __logf(1.f + __expf(-fabsf(g)));
}

// ---------------------------------------------------------------------------
// Kernel 1: P1p[n][o] = pack(bf16(n_feat[n]·W[o][0:64]), bf16(n_feat[n]·W[o+64][0:64]))
//           P2p same with k-range 64:128.
// Also (if deg != null) fused histogram of dst for the counting sort.
__global__ __launch_bounds__(256) void k_precompute(
    const float* __restrict__ n_feat, const float* __restrict__ W,
    unsigned* __restrict__ P1p, unsigned* __restrict__ P2p,
    const int* __restrict__ dst, unsigned* __restrict__ deg) {
  const int tid = threadIdx.x;
  if (deg) {
    for (int e = blockIdx.x * 256 + tid; e < N_EDGES; e += gridDim.x * 256)
      atomicAdd(&deg[dst[e]], 1u);
  }
  const int o   = tid & 63;
  const int sel = tid >> 6;                 // 0..3
  const int ch  = o + (sel & 1) * 64;
  const int kb  = (sel & 2) ? 64 : 0;
  float4 wreg[16];
  const float* wrow = W + (size_t)ch * IN_DIM + kb;
#pragma unroll
  for (int i = 0; i < 16; ++i) wreg[i] = *(const float4*)(wrow + i * 4);
  __shared__ float xrow[4][64];
  __shared__ float accbuf[4][4][64];        // [sel][r][o]
  for (int r0 = blockIdx.x * 4; r0 < N_NODES; r0 += gridDim.x * 4) {
    __syncthreads();
    xrow[tid >> 6][tid & 63] = n_feat[(size_t)(r0 + (tid >> 6)) * 64 + (tid & 63)];
    __syncthreads();
    float acc[4] = {0.f, 0.f, 0.f, 0.f};
#pragma unroll
    for (int kk = 0; kk < 16; ++kk) {
      float4 wv = wreg[kk];
#pragma unroll
      for (int r = 0; r < 4; ++r) {
        float4 xv = *(const float4*)&xrow[r][kk * 4];
        acc[r] += wv.x * xv.x + wv.y * xv.y + wv.z * xv.z + wv.w * xv.w;
      }
    }
#pragma unroll
    for (int r = 0; r < 4; ++r) accbuf[sel][r][o] = acc[r];
    __syncthreads();
    // thread (o, sel) packs+writes node row r0+sel
    const size_t rr = (size_t)(r0 + sel) * 64 + o;
    P1p[rr] = pack_bf16x2(accbuf[0][sel][o], accbuf[1][sel][o]);
    P2p[rr] = pack_bf16x2(accbuf[2][sel][o], accbuf[3][sel][o]);
  }
}

// ---------------------------------------------------------------------------
// Hierarchical exclusive scan of deg[N_NODES] -> offs/cursor.
// scan1: per-block (256 elems) sums.
__global__ __launch_bounds__(256) void k_scan1(const unsigned* __restrict__ deg,
                                               unsigned* __restrict__ bsum) {
  const int t = threadIdx.x;
  const int i = blockIdx.x * 256 + t;
  __shared__ unsigned r[256];
  r[t] = (i < N_NODES) ? deg[i] : 0u;
  __syncthreads();
  for (int off = 128; off > 0; off >>= 1) {
    if (t < off) r[t] += r[t + off];
    __syncthreads();
  }
  if (t == 0) bsum[blockIdx.x] = r[0];
}

// scan2: each block redundantly scans bsum[196] (cheap), then local scan.
__global__ __launch_bounds__(256) void k_scan2(const unsigned* __restrict__ deg,
                                               const unsigned* __restrict__ bsum,
                                               unsigned* __restrict__ offs,
                                               unsigned* __restrict__ cursor) {
  const int t = threadIdx.x;
  __shared__ unsigned sb[256];
  sb[t] = (t < NSCAN_BLOCKS) ? bsum[t] : 0u;
  __syncthreads();
  for (int off = 1; off < 256; off <<= 1) {
    unsigned add = (t >= off) ? sb[t - off] : 0u;
    __syncthreads();
    sb[t] += add;
    __syncthreads();
  }
  const unsigned base = (blockIdx.x == 0) ? 0u : sb[blockIdx.x - 1];
  const int i = blockIdx.x * 256 + t;
  const unsigned v = (i < N_NODES) ? deg[i] : 0u;
  __shared__ unsigned sd[256];
  sd[t] = v;
  __syncthreads();
  for (int off = 1; off < 256; off <<= 1) {
    unsigned add = (t >= off) ? sd[t - off] : 0u;
    __syncthreads();
    sd[t] += add;
    __syncthreads();
  }
  const unsigned excl = base + sd[t] - v;
  if (i < N_NODES) { offs[i] = excl; cursor[i] = excl; }
  if (blockIdx.x == 0 && t == 0) offs[N_NODES] = N_EDGES;
}

// rank[e] = slot of edge e in dst-sorted order (stable within a node not
// required; any bijection onto [offs[d], offs[d+1]) works).
__global__ __launch_bounds__(256) void k_scatter_ids(
    const int* __restrict__ dst, unsigned* __restrict__ cursor,
    unsigned* __restrict__ rank) {
  int e = blockIdx.x * 256 + threadIdx.x;
  if (e < N_EDGES) {
    rank[e] = atomicAdd(&cursor[dst[e]], 1u);
  }
}

// ---------------------------------------------------------------------------
// W3 fragment loader shared by edge kernels.
//   D-frag: lane holds D[m=(lane>>4)*4+r][n=nt*16+(lane&15)]
__device__ __forceinline__ void load_W3_frags(const float* __restrict__ W,
                                              int lane, bf16x8* Bf) {
  const int c = lane & 15, q = lane >> 4;
#pragma unroll
  for (int nt = 0; nt < 8; ++nt) {
#pragma unroll
    for (int ks = 0; ks < 2; ++ks) {
      const float* wr = W + (size_t)(nt * 16 + c) * IN_DIM + 128 + ks * 32 + q * 8;
      f32x4 w0 = *(const f32x4*)wr;
      f32x4 w1 = *(const f32x4*)(wr + 4);
      bf16x8 f;
#pragma unroll
      for (int j = 0; j < 4; ++j) { f[j] = (__bf16)w0[j]; f[4 + j] = (__bf16)w1[j]; }
      Bf[nt * 2 + ks] = f;
    }
  }
}

// ---------------------------------------------------------------------------
// Kernel 2: SEQUENTIAL edge order (coalesced e_feat/dst/src/rank streams).
// Wave computes h[16 edges][128 ch]; BN1 stats; hbuf store scattered to
// dst-sorted slot rank[e] (stores are fire-and-forget, randomizing the
// write side is free; each slot row is a full 256B).
// __launch_bounds__(256,6): VGPR<=85 -> 6 blocks/CU (was 3) for a
// latency-bound kernel; doubles resident waves.
__global__ __launch_bounds__(256, 6) void k_edge_h(
    const float* __restrict__ e_feat, const int* __restrict__ src,
    const int* __restrict__ dst, const unsigned* __restrict__ rank,
    const float* __restrict__ W, const float* __restrict__ b,
    const unsigned* __restrict__ P1p, const unsigned* __restrict__ P2p,
    float* __restrict__ stats1, unsigned int* __restrict__ hbuf) {
  const int tid = threadIdx.x, lane = tid & 63, w = tid >> 6;
  const int c = lane & 15, q = lane >> 4;
  bf16x8 Bf[16];
  load_W3_frags(W, lane, Bf);
  float bn_[8];
#pragma unroll
  for (int nt = 0; nt < 8; ++nt) bn_[nt] = b[nt * 16 + c];
  float sums[8] = {0, 0, 0, 0, 0, 0, 0, 0};
  float sqs[8]  = {0, 0, 0, 0, 0, 0, 0, 0};
  for (int g0 = blockIdx.x * 64; g0 < N_EDGES; g0 += gridDim.x * 64) {
    const int e0 = g0 + w * 16;
    // one coalesced load per stream, broadcast to r-slots via shfl
    // (lanes 0..15 hold the 16 edges' values)
    const int dv = dst[e0 + c];
    const int sv = src[e0 + c];
    const unsigned rv = rank ? rank[e0 + c] : 0u;
    const float* er = e_feat + (size_t)(e0 + c) * 64 + q * 8;
    f32x4 a0 = __builtin_nontemporal_load((const f32x4*)er);
    f32x4 a1 = __builtin_nontemporal_load((const f32x4*)(er + 4));
    f32x4 a2 = __builtin_nontemporal_load((const f32x4*)(er + 32));
    f32x4 a3 = __builtin_nontemporal_load((const f32x4*)(er + 36));
    int dIdx[4], sIdx[4], tIdx[4];
#pragma unroll
    for (int r = 0; r < 4; ++r) {
      dIdx[r] = __shfl(dv, q * 4 + r, 64);
      sIdx[r] = __shfl(sv, q * 4 + r, 64);
      tIdx[r] = rank ? (int)__shfl((int)rv, q * 4 + r, 64) : (e0 + q * 4 + r);
    }
    bf16x8 A0, A1;
#pragma unroll
    for (int j = 0; j < 4; ++j) {
      A0[j] = (__bf16)a0[j]; A0[4 + j] = (__bf16)a1[j];
      A1[j] = (__bf16)a2[j]; A1[4 + j] = (__bf16)a3[j];
    }
    f32x4 acc[8];
#pragma unroll
    for (int nt = 0; nt < 8; ++nt) {
      acc[nt] = (f32x4){0.f, 0.f, 0.f, 0.f};
      acc[nt] = __builtin_amdgcn_mfma_f32_16x16x32_bf16(A0, Bf[nt * 2 + 0], acc[nt], 0, 0, 0);
      acc[nt] = __builtin_amdgcn_mfma_f32_16x16x32_bf16(A1, Bf[nt * 2 + 1], acc[nt], 0, 0, 0);
    }
    float h[8][4];
#pragma unroll
    for (int r = 0; r < 4; ++r) {
      const unsigned* p1r = P1p + (size_t)dIdx[r] * 64 + c;
      const unsigned* p2r = P2p + (size_t)sIdx[r] * 64 + c;
#pragma unroll
      for (int ntp = 0; ntp < 4; ++ntp) {
        unsigned u1 = p1r[ntp * 16];
        unsigned u2 = p2r[ntp * 16];
        float lo = __uint_as_float(u1 << 16) + __uint_as_float(u2 << 16);
        float hi = __uint_as_float(u1 & 0xffff0000u) + __uint_as_float(u2 & 0xffff0000u);
        h[ntp][r]     = acc[ntp][r]     + lo + bn_[ntp];
        h[ntp + 4][r] = acc[ntp + 4][r] + hi + bn_[ntp + 4];
      }
    }
#pragma unroll
    for (int nt = 0; nt < 8; ++nt)
#pragma unroll
      for (int r = 0; r < 4; ++r) {
        sums[nt] += h[nt][r];
        sqs[nt]  += h[nt][r] * h[nt][r];
      }
    if (hbuf) {
#pragma unroll
      for (int r = 0; r < 4; ++r) {
        unsigned int* hb = hbuf + (size_t)tIdx[r] * 64 + c;
#pragma unroll
        for (int nt = 0; nt < 4; ++nt)
          hb[nt * 16] = pack_bf16x2(h[nt][r], h[nt + 4][r]);
      }
    }
  }
  __shared__ float red[4][256];
#pragma unroll
  for (int nt = 0; nt < 8; ++nt) {
    float s = sums[nt]; s += __shfl_xor(s, 16, 64); s += __shfl_xor(s, 32, 64);
    float qv = sqs[nt]; qv += __shfl_xor(qv, 16, 64); qv += __shfl_xor(qv, 32, 64);
    if (lane < 16) { red[w][nt * 16 + lane] = s; red[w][128 + nt * 16 + lane] = qv; }
  }
  __syncthreads();
  float v = red[0][tid] + red[1][tid] + red[2][tid] + red[3][tid];
  unsafeAtomicAdd(&stats1[tid], v);
}

// Kernel 3: fold BN1 into per-channel affine.
__global__ void k_finalize1(const float* __restrict__ stats1,
                            const float* __restrict__ g1,
                            const float* __restrict__ beta1,
                            float* __restrict__ ss1) {
  int t = threadIdx.x;
  if (t < 128) {
    float inv_n = 1.f / (float)N_EDGES;
    float mu  = stats1[t] * inv_n;
    float var = stats1[128 + t] * inv_n - mu * mu;
    float sc  = g1[t] * rsqrtf(var + BN_EPS);
    ss1[t] = sc;
    ss1[128 + t] = beta1[t] - mu * sc;
  }
}

__device__ __forceinline__ float msg_of(unsigned p, float sc_f, float sh_f,
                                        float sc_g, float sh_g) {
  float f = __uint_as_float(p << 16) * sc_f + sh_f;
  float g = __uint_as_float(p & 0xffff0000u) * sc_g + sh_g;
  return fast_sigmoid(f) * fast_softplus(g);
}

// ---------------------------------------------------------------------------
// Kernel 4 (sorted): hbuf is in dst-sorted slot order, so node n owns the
// contiguous slot range [offs[n], offs[n+1]).  Streaming cached reads (hbuf
// lines mostly L3-resident from the edge-pass stores), BN1 affine,
// msg=sigmoid*softplus, register-accumulate, single agg write.
// Fuses BN2 stats (no k_agg_stats, no agg memset, zero atomics on agg).
__global__ __launch_bounds__(256) void k_gather_msg(
    const unsigned int* __restrict__ hbuf, const unsigned* __restrict__ offs,
    const float* __restrict__ ss1, float* __restrict__ agg,
    float* __restrict__ stats2) {
  const int tid = threadIdx.x, lane = tid & 63, w = tid >> 6;
  const float sc_f = ss1[lane], sc_g = ss1[64 + lane];
  const float sh_f = ss1[128 + lane], sh_g = ss1[192 + lane];
  const int wave_id = blockIdx.x * 4 + w;
  const int n_waves = gridDim.x * 4;
  float ssum = 0.f, ssq = 0.f;
  for (int node = wave_id; node < N_NODES; node += n_waves) {
    const int start = (int)offs[node], end = (int)offs[node + 1];
    float acc = 0.f;
    int j = start;
    for (; j + 8 <= end; j += 8) {
      unsigned p[8];
#pragma unroll
      for (int k = 0; k < 8; ++k) p[k] = hbuf[(size_t)(j + k) * 64 + lane];
#pragma unroll
      for (int k = 0; k < 8; ++k) acc += msg_of(p[k], sc_f, sh_f, sc_g, sh_g);
    }
    for (; j < end; ++j)
      acc += msg_of(hbuf[(size_t)j * 64 + lane], sc_f, sh_f, sc_g, sh_g);
    agg[(size_t)node * 64 + lane] = acc;
    ssum += acc; ssq += acc * acc;
  }
  __shared__ float red[4][64], redq[4][64];
  red[w][lane] = ssum; redq[w][lane] = ssq;
  __syncthreads();
  if (tid < 64) {
    unsafeAtomicAdd(&stats2[tid], red[0][tid] + red[1][tid] + red[2][tid] + red[3][tid]);
  } else if (tid < 128) {
    int t = tid - 64;
    unsafeAtomicAdd(&stats2[64 + t], redq[0][t] + redq[1][t] + redq[2][t] + redq[3][t]);
  }
}

// ---------------------------------------------------------------------------
// Kernel 4 (fallback, atomic): read packed h (edge order), BN1 affine, msg,
// scatter.
__global__ __launch_bounds__(256) void k_msg_scatter(
    const unsigned int* __restrict__ hbuf, const int* __restrict__ dst,
    const float* __restrict__ ss1, float* __restrict__ agg) {
  const int tid = threadIdx.x, lane = tid & 63, w = tid >> 6;
  const float sc_f = ss1[lane], sc_g = ss1[64 + lane];
  const float sh_f = ss1[128 + lane], sh_g = ss1[192 + lane];
  const int wave_id = blockIdx.x * 4 + w;
  const int n_waves = gridDim.x * 4;
  for (int e0 = wave_id * 8; e0 < N_EDGES; e0 += n_waves * 8) {
    unsigned int p[8];
    int d[8];
#pragma unroll
    for (int j = 0; j < 8; ++j) {
      p[j] = hbuf[(size_t)(e0 + j) * 64 + lane];
      d[j] = __builtin_amdgcn_readfirstlane(dst[e0 + j]);
    }
#pragma unroll
    for (int j = 0; j < 8; ++j) {
      unsafeAtomicAdd(&agg[(size_t)d[j] * 64 + lane],
                      msg_of(p[j], sc_f, sh_f, sc_g, sh_g));
    }
  }
}

// Fallback pass 2 (recompute h) if ws_size is too small for hbuf.
__global__ __launch_bounds__(256, 3) void k_edge_msg(
    const float* __restrict__ e_feat, const int* __restrict__ src,
    const int* __restrict__ dst, const float* __restrict__ W,
    const float* __restrict__ b, const unsigned* __restrict__ P1p,
    const unsigned* __restrict__ P2p, const float* __restrict__ ss1,
    float* __restrict__ agg) {
  const int tid = threadIdx.x, lane = tid & 63, w = tid >> 6;
  const int c = lane & 15, q = lane >> 4;
  bf16x8 Bf[16];
  load_W3_frags(W, lane, Bf);
  float bn_[8], sc[8], sh[8];
#pragma unroll
  for (int nt = 0; nt < 8; ++nt) {
    bn_[nt] = b[nt * 16 + c];
    sc[nt]  = ss1[nt * 16 + c];
    sh[nt]  = ss1[128 + nt * 16 + c];
  }
  for (int g0 = blockIdx.x * 64; g0 < N_EDGES; g0 += gridDim.x * 64) {
    const int e0 = g0 + w * 16;
    const int dv = dst[e0 + c];
    const int sv = src[e0 + c];
    const float* er = e_feat + (size_t)(e0 + c) * 64 + q * 8;
    f32x4 a0 = __builtin_nontemporal_load((const f32x4*)er);
    f32x4 a1 = __builtin_nontemporal_load((const f32x4*)(er + 4));
    f32x4 a2 = __builtin_nontemporal_load((const f32x4*)(er + 32));
    f32x4 a3 = __builtin_nontemporal_load((const f32x4*)(er + 36));
    int dIdx[4], sIdx[4];
#pragma unroll
    for (int r = 0; r < 4; ++r) {
      dIdx[r] = __shfl(dv, q * 4 + r, 64);
      sIdx[r] = __shfl(sv, q * 4 + r, 64);
    }
    bf16x8 A0, A1;
#pragma unroll
    for (int j = 0; j < 4; ++j) {
      A0[j] = (__bf16)a0[j]; A0[4 + j] = (__bf16)a1[j];
      A1[j] = (__bf16)a2[j]; A1[4 + j] = (__bf16)a3[j];
    }
    f32x4 acc[8];
#pragma unroll
    for (int nt = 0; nt < 8; ++nt) {
      acc[nt] = (f32x4){0.f, 0.f, 0.f, 0.f};
      acc[nt] = __builtin_amdgcn_mfma_f32_16x16x32_bf16(A0, Bf[nt * 2 + 0], acc[nt], 0, 0, 0);
      acc[nt] = __builtin_amdgcn_mfma_f32_16x16x32_bf16(A1, Bf[nt * 2 + 1], acc[nt], 0, 0, 0);
    }
#pragma unroll
    for (int r = 0; r < 4; ++r) {
      const unsigned* p1r = P1p + (size_t)dIdx[r] * 64 + c;
      const unsigned* p2r = P2p + (size_t)sIdx[r] * 64 + c;
#pragma unroll
      for (int ntp = 0; ntp < 4; ++ntp) {
        unsigned u1 = p1r[ntp * 16];
        unsigned u2 = p2r[ntp * 16];
        float lo = __uint_as_float(u1 << 16) + __uint_as_float(u2 << 16);
        float hi = __uint_as_float(u1 & 0xffff0000u) + __uint_as_float(u2 & 0xffff0000u);
        float hval_lo = acc[ntp][r]     + lo + bn_[ntp];
        float hval_hi = acc[ntp + 4][r] + hi + bn_[ntp + 4];
        float f = hval_lo * sc[ntp] + sh[ntp];
        float g = hval_hi * sc[ntp + 4] + sh[ntp + 4];
        unsafeAtomicAdd(&agg[(size_t)dIdx[r] * 64 + ntp * 16 + c],
                        fast_sigmoid(f) * fast_softplus(g));
      }
    }
  }
}

// Kernel 5: BN2 stats over agg rows (fallback paths only).
__global__ __launch_bounds__(256) void k_agg_stats(const float* __restrict__ agg,
                                                   float* __restrict__ stats2) {
  const int tid = threadIdx.x;
  const int c = tid & 63, w = tid >> 6;
  float s = 0.f, sq = 0.f;
  for (int r = blockIdx.x * 4 + w; r < N_NODES; r += gridDim.x * 4) {
    float v = agg[(size_t)r * 64 + c];
    s += v; sq += v * v;
  }
  __shared__ float ws_[4][64], wq_[4][64];
  ws_[w][c] = s; wq_[w][c] = sq;
  __syncthreads();
  if (tid < 64) {
    unsafeAtomicAdd(&stats2[tid], ws_[0][tid] + ws_[1][tid] + ws_[2][tid] + ws_[3][tid]);
  } else if (tid < 128) {
    int t = tid - 64;
    unsafeAtomicAdd(&stats2[64 + t], wq_[0][t] + wq_[1][t] + wq_[2][t] + wq_[3][t]);
  }
}

__global__ void k_finalize2(const float* __restrict__ stats2,
                            const float* __restrict__ g2,
                            const float* __restrict__ beta2,
                            float* __restrict__ ss2) {
  int t = threadIdx.x;
  if (t < 64) {
    float inv_n = 1.f / (float)N_NODES;
    float mu  = stats2[t] * inv_n;
    float var = stats2[64 + t] * inv_n - mu * mu;
    float sc  = g2[t] * rsqrtf(var + BN_EPS);
    ss2[t] = sc;
    ss2[64 + t] = beta2[t] - mu * sc;
  }
}

// Kernel 7: out = softplus(BN2(agg) + n_feat), float4-vectorized.
__global__ __launch_bounds__(256) void k_output(const float* __restrict__ agg,
                                                const float* __restrict__ n_feat,
                                                const float* __restrict__ ss2,
                                                float* __restrict__ out) {
  int i = blockIdx.x * 256 + threadIdx.x;
  if (i >= N_NODES * 16) return;
  int cb = (i & 15) * 4;
  float4 a = ((const float4*)agg)[i];
  float4 x = ((const float4*)n_feat)[i];
  float4 r;
  r.x = fast_softplus(a.x * ss2[cb + 0] + ss2[64 + cb + 0] + x.x);
  r.y = fast_softplus(a.y * ss2[cb + 1] + ss2[64 + cb + 1] + x.y);
  r.z = fast_softplus(a.z * ss2[cb + 2] + ss2[64 + cb + 2] + x.z);
  r.w = fast_softplus(a.w * ss2[cb + 3] + ss2[64 + cb + 3] + x.w);
  ((float4*)out)[i] = r;
}

extern "C" void kernel_launch(void* const* d_in, const int* in_sizes, int n_in,
                              void* d_out, int out_size, void* d_ws, size_t ws_size,
                              hipStream_t stream) {
  const float* n_feat = (const float*)d_in[0];
  const float* e_feat = (const float*)d_in[1];
  const int*   src    = (const int*)d_in[2];
  const int*   dst    = (const int*)d_in[3];
  const float* W      = (const float*)d_in[4];
  const float* b      = (const float*)d_in[5];
  const float* g1     = (const float*)d_in[6];
  const float* beta1  = (const float*)d_in[7];
  const float* g2     = (const float*)d_in[8];
  const float* beta2  = (const float*)d_in[9];

  unsigned* ws  = (unsigned*)d_ws;
  unsigned* P1p = ws;
  unsigned* P2p = ws + OFF_P2P;
  float* agg    = (float*)(ws + OFF_AGG);
  float* stats1 = (float*)(ws + OFF_STATS1);
  float* ss1    = stats1 + 256;
  float* stats2 = ss1 + 256;
  float* ss2    = stats2 + 128;
  unsigned int* hbuf = ws + OFF_HBUF;
  unsigned* rank   = ws + OFF_RANK;
  unsigned* offs   = ws + OFF_OFFS;
  unsigned* deg    = ws + OFF_DEG;
  unsigned* cursor = ws + OFF_CURS;
  unsigned* bsum   = ws + OFF_BSUM;
  float* out    = (float*)d_out;

  const bool have_hbuf = ws_size >= WS_WORDS_NEEDED * 4;
  const bool have_sort = ws_size >= WS_WORDS_SORTED * 4;

  hipMemsetAsync(stats1, 0, (256 + 256 + 128 + 128) * sizeof(float), stream);

  if (have_sort) {
    hipMemsetAsync(deg, 0, N_NODES * sizeof(unsigned), stream);
    // precompute P tables + fused dst histogram
    k_precompute<<<1024, 256, 0, stream>>>(n_feat, W, P1p, P2p, dst, deg);
    // hierarchical scan
    k_scan1<<<NSCAN_BLOCKS, 256, 0, stream>>>(deg, bsum);
    k_scan2<<<NSCAN_BLOCKS, 256, 0, stream>>>(deg, bsum, offs, cursor);
    k_scatter_ids<<<(N_EDGES + 255) / 256, 256, 0, stream>>>(dst, cursor, rank);
    // sequential-order edge pass, hbuf stores scattered to sorted slots
    k_edge_h<<<2048, 256, 0, stream>>>(e_feat, src, dst, rank, W, b,
                                       P1p, P2p, stats1, hbuf);
    k_finalize1<<<1, 128, 0, stream>>>(stats1, g1, beta1, ss1);
    // pure streaming gather: no indirection, no atomics, fuses BN2 stats
    k_gather_msg<<<2048, 256, 0, stream>>>(hbuf, offs, ss1, agg, stats2);
  } else {
    hipMemsetAsync(agg, 0, (size_t)N_NODES * 64 * sizeof(float), stream);
    k_precompute<<<1024, 256, 0, stream>>>(n_feat, W, P1p, P2p, dst, nullptr);
    if (have_hbuf) {
      k_edge_h<<<2048, 256, 0, stream>>>(e_feat, src, dst, nullptr, W, b,
                                         P1p, P2p, stats1, hbuf);
      k_finalize1<<<1, 128, 0, stream>>>(stats1, g1, beta1, ss1);
      k_msg_scatter<<<2048, 256, 0, stream>>>(hbuf, dst, ss1, agg);
    } else {
      k_edge_h<<<2048, 256, 0, stream>>>(e_feat, src, dst, nullptr, W, b,
                                         P1p, P2p, stats1, nullptr);
      k_finalize1<<<1, 128, 0, stream>>>(stats1, g1, beta1, ss1);
      k_edge_msg<<<2048, 256, 0, stream>>>(e_feat, src, dst, W, b, P1p, P2p, ss1, agg);
    }
    k_agg_stats<<<512, 256, 0, stream>>>(agg, stats2);
  }
  k_finalize2<<<1, 64, 0, stream>>>(stats2, g2, beta2, ss2);
  k_output<<<3125, 256, 0, stream>>>(agg, n_feat, ss2, out);
}

// Round 6
// 682.559 us; speedup vs baseline: 1.1803x; 1.1803x over previous
//
#include <hip/hip_runtime.h>
#include <math.h>

// Problem constants (from reference)
#define N_NODES 50000
#define N_EDGES 800000
#define IN_DIM  192      // 2*O + ED
#define BN_EPS  1e-5f

// Workspace layout (4-byte word offsets):
//   P1p    [N,64]  uint @ 0          packed bf16x2 {chan n, chan n+64} of n_feat@W1^T
//   P2p    [N,64]  uint @ 3,200,000  same for W2^T
//   agg    [N,64]  f32  @ 6,400,000
//   stats1 [256]   f32  @ 9,600,000  (sum[128], sumsq[128])
//   ss1    [256]   f32  @ +256       (scale[128], shift[128])
//   stats2 [128]   f32  @ +512
//   ss2    [128]   f32  @ +640
//   hbuf   [E,64]  uint @ 9,601,024  packed bf16x2 {filt,core} at SORTED slot
//   rank   [E]     uint @ OFF_RANK   slot index of edge e in dst-sorted order
//   offs   [N+1]   uint @ OFF_OFFS   CSR row offsets per dst node
//   deg    [N]     uint @ OFF_DEG    histogram scratch
//   cursor [N]     uint @ OFF_CURS   scatter cursors (copy of offs)
//   bsum   [256]   uint @ OFF_BSUM   per-block sums for hierarchical scan
#define OFF_P2P    3200000
#define OFF_AGG    6400000
#define OFF_STATS1 9600000
#define OFF_HBUF   9601024
#define WS_WORDS_NEEDED (OFF_HBUF + (size_t)N_EDGES * 64)
#define OFF_RANK   (OFF_HBUF + (size_t)N_EDGES * 64)
#define OFF_OFFS   (OFF_RANK + N_EDGES)
#define OFF_DEG    (OFF_OFFS + N_NODES + 1)
#define OFF_CURS   (OFF_DEG + N_NODES)
#define OFF_BSUM   (OFF_CURS + N_NODES)
#define WS_WORDS_SORTED (OFF_BSUM + 256)

#define NSCAN_BLOCKS 196   // ceil(50000/256)

typedef __bf16 bf16x8 __attribute__((ext_vector_type(8)));
typedef __bf16 bf16x2 __attribute__((ext_vector_type(2)));
typedef float  f32x4  __attribute__((ext_vector_type(4)));

__device__ __forceinline__ unsigned pack_bf16x2(float lo, float hi) {
  union { bf16x2 v; unsigned u; } pk;
  pk.v[0] = (__bf16)lo; pk.v[1] = (__bf16)hi;
  return pk.u;
}
// fast transcendentals (native v_exp/v_log/v_rcp)
__device__ __forceinline__ float fast_sigmoid(float f) {
  return __builtin_amdgcn_rcpf(1.f + __expf(-f));
}
__device__ __forceinline__ float fast_softplus(float g) {
  return fmaxf(g, 0.f) + __logf(1.f + __expf(-fabsf(g)));
}

// ---------------------------------------------------------------------------
// Kernel 1: P1p[n][o] = pack(bf16(n_feat[n]·W[o][0:64]), bf16(n_feat[n]·W[o+64][0:64]))
//           P2p same with k-range 64:128.
// Also (if deg != null) fused histogram of dst for the counting sort.
__global__ __launch_bounds__(256) void k_precompute(
    const float* __restrict__ n_feat, const float* __restrict__ W,
    unsigned* __restrict__ P1p, unsigned* __restrict__ P2p,
    const int* __restrict__ dst, unsigned* __restrict__ deg) {
  const int tid = threadIdx.x;
  if (deg) {
    for (int e = blockIdx.x * 256 + tid; e < N_EDGES; e += gridDim.x * 256)
      atomicAdd(&deg[dst[e]], 1u);
  }
  const int o   = tid & 63;
  const int sel = tid >> 6;                 // 0..3
  const int ch  = o + (sel & 1) * 64;
  const int kb  = (sel & 2) ? 64 : 0;
  float4 wreg[16];
  const float* wrow = W + (size_t)ch * IN_DIM + kb;
#pragma unroll
  for (int i = 0; i < 16; ++i) wreg[i] = *(const float4*)(wrow + i * 4);
  __shared__ float xrow[4][64];
  __shared__ float accbuf[4][4][64];        // [sel][r][o]
  for (int r0 = blockIdx.x * 4; r0 < N_NODES; r0 += gridDim.x * 4) {
    __syncthreads();
    xrow[tid >> 6][tid & 63] = n_feat[(size_t)(r0 + (tid >> 6)) * 64 + (tid & 63)];
    __syncthreads();
    float acc[4] = {0.f, 0.f, 0.f, 0.f};
#pragma unroll
    for (int kk = 0; kk < 16; ++kk) {
      float4 wv = wreg[kk];
#pragma unroll
      for (int r = 0; r < 4; ++r) {
        float4 xv = *(const float4*)&xrow[r][kk * 4];
        acc[r] += wv.x * xv.x + wv.y * xv.y + wv.z * xv.z + wv.w * xv.w;
      }
    }
#pragma unroll
    for (int r = 0; r < 4; ++r) accbuf[sel][r][o] = acc[r];
    __syncthreads();
    // thread (o, sel) packs+writes node row r0+sel
    const size_t rr = (size_t)(r0 + sel) * 64 + o;
    P1p[rr] = pack_bf16x2(accbuf[0][sel][o], accbuf[1][sel][o]);
    P2p[rr] = pack_bf16x2(accbuf[2][sel][o], accbuf[3][sel][o]);
  }
}

// ---------------------------------------------------------------------------
// Hierarchical exclusive scan of deg[N_NODES] -> offs/cursor.
// scan1: per-block (256 elems) sums.
__global__ __launch_bounds__(256) void k_scan1(const unsigned* __restrict__ deg,
                                               unsigned* __restrict__ bsum) {
  const int t = threadIdx.x;
  const int i = blockIdx.x * 256 + t;
  __shared__ unsigned r[256];
  r[t] = (i < N_NODES) ? deg[i] : 0u;
  __syncthreads();
  for (int off = 128; off > 0; off >>= 1) {
    if (t < off) r[t] += r[t + off];
    __syncthreads();
  }
  if (t == 0) bsum[blockIdx.x] = r[0];
}

// scan2: each block redundantly scans bsum[196] (cheap), then local scan.
__global__ __launch_bounds__(256) void k_scan2(const unsigned* __restrict__ deg,
                                               const unsigned* __restrict__ bsum,
                                               unsigned* __restrict__ offs,
                                               unsigned* __restrict__ cursor) {
  const int t = threadIdx.x;
  __shared__ unsigned sb[256];
  sb[t] = (t < NSCAN_BLOCKS) ? bsum[t] : 0u;
  __syncthreads();
  for (int off = 1; off < 256; off <<= 1) {
    unsigned add = (t >= off) ? sb[t - off] : 0u;
    __syncthreads();
    sb[t] += add;
    __syncthreads();
  }
  const unsigned base = (blockIdx.x == 0) ? 0u : sb[blockIdx.x - 1];
  const int i = blockIdx.x * 256 + t;
  const unsigned v = (i < N_NODES) ? deg[i] : 0u;
  __shared__ unsigned sd[256];
  sd[t] = v;
  __syncthreads();
  for (int off = 1; off < 256; off <<= 1) {
    unsigned add = (t >= off) ? sd[t - off] : 0u;
    __syncthreads();
    sd[t] += add;
    __syncthreads();
  }
  const unsigned excl = base + sd[t] - v;
  if (i < N_NODES) { offs[i] = excl; cursor[i] = excl; }
  if (blockIdx.x == 0 && t == 0) offs[N_NODES] = N_EDGES;
}

// rank[e] = slot of edge e in dst-sorted order (stable within a node not
// required; any bijection onto [offs[d], offs[d+1]) works).
__global__ __launch_bounds__(256) void k_scatter_ids(
    const int* __restrict__ dst, unsigned* __restrict__ cursor,
    unsigned* __restrict__ rank) {
  int e = blockIdx.x * 256 + threadIdx.x;
  if (e < N_EDGES) {
    rank[e] = atomicAdd(&cursor[dst[e]], 1u);
  }
}

// ---------------------------------------------------------------------------
// W3 fragment loader shared by edge kernels.
//   D-frag: lane holds D[m=(lane>>4)*4+r][n=nt*16+(lane&15)]
__device__ __forceinline__ void load_W3_frags(const float* __restrict__ W,
                                              int lane, bf16x8* Bf) {
  const int c = lane & 15, q = lane >> 4;
#pragma unroll
  for (int nt = 0; nt < 8; ++nt) {
#pragma unroll
    for (int ks = 0; ks < 2; ++ks) {
      const float* wr = W + (size_t)(nt * 16 + c) * IN_DIM + 128 + ks * 32 + q * 8;
      f32x4 w0 = *(const f32x4*)wr;
      f32x4 w1 = *(const f32x4*)(wr + 4);
      bf16x8 f;
#pragma unroll
      for (int j = 0; j < 4; ++j) { f[j] = (__bf16)w0[j]; f[4 + j] = (__bf16)w1[j]; }
      Bf[nt * 2 + ks] = f;
    }
  }
}

// ---------------------------------------------------------------------------
// Kernel 2: SEQUENTIAL edge order (coalesced e_feat/dst/src/rank streams).
// Wave computes h[16 edges][128 ch]; BN1 stats; hbuf store scattered to
// dst-sorted slot rank[e].
// __launch_bounds__(256,4): register budget 128 >= need (~84 VGPR + 32 AGPR
// accumulators = ~116) -> 4 waves/SIMD with ZERO spill.  (256,6) in the
// previous round demanded <=85 regs and spilled catastrophically
// (FETCH 289->847 MB of scratch traffic).
__global__ __launch_bounds__(256, 4) void k_edge_h(
    const float* __restrict__ e_feat, const int* __restrict__ src,
    const int* __restrict__ dst, const unsigned* __restrict__ rank,
    const float* __restrict__ W, const float* __restrict__ b,
    const unsigned* __restrict__ P1p, const unsigned* __restrict__ P2p,
    float* __restrict__ stats1, unsigned int* __restrict__ hbuf) {
  const int tid = threadIdx.x, lane = tid & 63, w = tid >> 6;
  const int c = lane & 15, q = lane >> 4;
  bf16x8 Bf[16];
  load_W3_frags(W, lane, Bf);
  float bn_[8];
#pragma unroll
  for (int nt = 0; nt < 8; ++nt) bn_[nt] = b[nt * 16 + c];
  float sums[8] = {0, 0, 0, 0, 0, 0, 0, 0};
  float sqs[8]  = {0, 0, 0, 0, 0, 0, 0, 0};
  for (int g0 = blockIdx.x * 64; g0 < N_EDGES; g0 += gridDim.x * 64) {
    const int e0 = g0 + w * 16;
    // one coalesced load per stream, broadcast to r-slots via shfl
    // (lanes 0..15 hold the 16 edges' values)
    const int dv = dst[e0 + c];
    const int sv = src[e0 + c];
    const unsigned rv = rank ? rank[e0 + c] : 0u;
    const float* er = e_feat + (size_t)(e0 + c) * 64 + q * 8;
    f32x4 a0 = __builtin_nontemporal_load((const f32x4*)er);
    f32x4 a1 = __builtin_nontemporal_load((const f32x4*)(er + 4));
    f32x4 a2 = __builtin_nontemporal_load((const f32x4*)(er + 32));
    f32x4 a3 = __builtin_nontemporal_load((const f32x4*)(er + 36));
    int dIdx[4], sIdx[4], tIdx[4];
#pragma unroll
    for (int r = 0; r < 4; ++r) {
      dIdx[r] = __shfl(dv, q * 4 + r, 64);
      sIdx[r] = __shfl(sv, q * 4 + r, 64);
      tIdx[r] = rank ? (int)__shfl((int)rv, q * 4 + r, 64) : (e0 + q * 4 + r);
    }
    bf16x8 A0, A1;
#pragma unroll
    for (int j = 0; j < 4; ++j) {
      A0[j] = (__bf16)a0[j]; A0[4 + j] = (__bf16)a1[j];
      A1[j] = (__bf16)a2[j]; A1[4 + j] = (__bf16)a3[j];
    }
    f32x4 acc[8];
#pragma unroll
    for (int nt = 0; nt < 8; ++nt) {
      acc[nt] = (f32x4){0.f, 0.f, 0.f, 0.f};
      acc[nt] = __builtin_amdgcn_mfma_f32_16x16x32_bf16(A0, Bf[nt * 2 + 0], acc[nt], 0, 0, 0);
      acc[nt] = __builtin_amdgcn_mfma_f32_16x16x32_bf16(A1, Bf[nt * 2 + 1], acc[nt], 0, 0, 0);
    }
    float h[8][4];
#pragma unroll
    for (int r = 0; r < 4; ++r) {
      const unsigned* p1r = P1p + (size_t)dIdx[r] * 64 + c;
      const unsigned* p2r = P2p + (size_t)sIdx[r] * 64 + c;
#pragma unroll
      for (int ntp = 0; ntp < 4; ++ntp) {
        unsigned u1 = p1r[ntp * 16];
        unsigned u2 = p2r[ntp * 16];
        float lo = __uint_as_float(u1 << 16) + __uint_as_float(u2 << 16);
        float hi = __uint_as_float(u1 & 0xffff0000u) + __uint_as_float(u2 & 0xffff0000u);
        h[ntp][r]     = acc[ntp][r]     + lo + bn_[ntp];
        h[ntp + 4][r] = acc[ntp + 4][r] + hi + bn_[ntp + 4];
      }
    }
#pragma unroll
    for (int nt = 0; nt < 8; ++nt)
#pragma unroll
      for (int r = 0; r < 4; ++r) {
        sums[nt] += h[nt][r];
        sqs[nt]  += h[nt][r] * h[nt][r];
      }
    if (hbuf) {
#pragma unroll
      for (int r = 0; r < 4; ++r) {
        unsigned int* hb = hbuf + (size_t)tIdx[r] * 64 + c;
#pragma unroll
        for (int nt = 0; nt < 4; ++nt)
          hb[nt * 16] = pack_bf16x2(h[nt][r], h[nt + 4][r]);
      }
    }
  }
  __shared__ float red[4][256];
#pragma unroll
  for (int nt = 0; nt < 8; ++nt) {
    float s = sums[nt]; s += __shfl_xor(s, 16, 64); s += __shfl_xor(s, 32, 64);
    float qv = sqs[nt]; qv += __shfl_xor(qv, 16, 64); qv += __shfl_xor(qv, 32, 64);
    if (lane < 16) { red[w][nt * 16 + lane] = s; red[w][128 + nt * 16 + lane] = qv; }
  }
  __syncthreads();
  float v = red[0][tid] + red[1][tid] + red[2][tid] + red[3][tid];
  unsafeAtomicAdd(&stats1[tid], v);
}

// Kernel 3: fold BN1 into per-channel affine.
__global__ void k_finalize1(const float* __restrict__ stats1,
                            const float* __restrict__ g1,
                            const float* __restrict__ beta1,
                            float* __restrict__ ss1) {
  int t = threadIdx.x;
  if (t < 128) {
    float inv_n = 1.f / (float)N_EDGES;
    float mu  = stats1[t] * inv_n;
    float var = stats1[128 + t] * inv_n - mu * mu;
    float sc  = g1[t] * rsqrtf(var + BN_EPS);
    ss1[t] = sc;
    ss1[128 + t] = beta1[t] - mu * sc;
  }
}

__device__ __forceinline__ float msg_of(unsigned p, float sc_f, float sh_f,
                                        float sc_g, float sh_g) {
  float f = __uint_as_float(p << 16) * sc_f + sh_f;
  float g = __uint_as_float(p & 0xffff0000u) * sc_g + sh_g;
  return fast_sigmoid(f) * fast_softplus(g);
}

// ---------------------------------------------------------------------------
// Kernel 4 (sorted): hbuf is in dst-sorted slot order, so node n owns the
// contiguous slot range [offs[n], offs[n+1]).  Streaming cached reads (hbuf
// lines mostly L3-resident from the edge-pass stores), BN1 affine,
// msg=sigmoid*softplus, register-accumulate, single agg write.
// Fuses BN2 stats (no k_agg_stats, no agg memset, zero atomics on agg).
__global__ __launch_bounds__(256) void k_gather_msg(
    const unsigned int* __restrict__ hbuf, const unsigned* __restrict__ offs,
    const float* __restrict__ ss1, float* __restrict__ agg,
    float* __restrict__ stats2) {
  const int tid = threadIdx.x, lane = tid & 63, w = tid >> 6;
  const float sc_f = ss1[lane], sc_g = ss1[64 + lane];
  const float sh_f = ss1[128 + lane], sh_g = ss1[192 + lane];
  const int wave_id = blockIdx.x * 4 + w;
  const int n_waves = gridDim.x * 4;
  float ssum = 0.f, ssq = 0.f;
  for (int node = wave_id; node < N_NODES; node += n_waves) {
    const int start = (int)offs[node], end = (int)offs[node + 1];
    float acc = 0.f;
    int j = start;
    for (; j + 8 <= end; j += 8) {
      unsigned p[8];
#pragma unroll
      for (int k = 0; k < 8; ++k) p[k] = hbuf[(size_t)(j + k) * 64 + lane];
#pragma unroll
      for (int k = 0; k < 8; ++k) acc += msg_of(p[k], sc_f, sh_f, sc_g, sh_g);
    }
    for (; j < end; ++j)
      acc += msg_of(hbuf[(size_t)j * 64 + lane], sc_f, sh_f, sc_g, sh_g);
    agg[(size_t)node * 64 + lane] = acc;
    ssum += acc; ssq += acc * acc;
  }
  __shared__ float red[4][64], redq[4][64];
  red[w][lane] = ssum; redq[w][lane] = ssq;
  __syncthreads();
  if (tid < 64) {
    unsafeAtomicAdd(&stats2[tid], red[0][tid] + red[1][tid] + red[2][tid] + red[3][tid]);
  } else if (tid < 128) {
    int t = tid - 64;
    unsafeAtomicAdd(&stats2[64 + t], redq[0][t] + redq[1][t] + redq[2][t] + redq[3][t]);
  }
}

// ---------------------------------------------------------------------------
// Kernel 4 (fallback, atomic): read packed h (edge order), BN1 affine, msg,
// scatter.
__global__ __launch_bounds__(256) void k_msg_scatter(
    const unsigned int* __restrict__ hbuf, const int* __restrict__ dst,
    const float* __restrict__ ss1, float* __restrict__ agg) {
  const int tid = threadIdx.x, lane = tid & 63, w = tid >> 6;
  const float sc_f = ss1[lane], sc_g = ss1[64 + lane];
  const float sh_f = ss1[128 + lane], sh_g = ss1[192 + lane];
  const int wave_id = blockIdx.x * 4 + w;
  const int n_waves = gridDim.x * 4;
  for (int e0 = wave_id * 8; e0 < N_EDGES; e0 += n_waves * 8) {
    unsigned int p[8];
    int d[8];
#pragma unroll
    for (int j = 0; j < 8; ++j) {
      p[j] = hbuf[(size_t)(e0 + j) * 64 + lane];
      d[j] = __builtin_amdgcn_readfirstlane(dst[e0 + j]);
    }
#pragma unroll
    for (int j = 0; j < 8; ++j) {
      unsafeAtomicAdd(&agg[(size_t)d[j] * 64 + lane],
                      msg_of(p[j], sc_f, sh_f, sc_g, sh_g));
    }
  }
}

// Fallback pass 2 (recompute h) if ws_size is too small for hbuf.
__global__ __launch_bounds__(256, 3) void k_edge_msg(
    const float* __restrict__ e_feat, const int* __restrict__ src,
    const int* __restrict__ dst, const float* __restrict__ W,
    const float* __restrict__ b, const unsigned* __restrict__ P1p,
    const unsigned* __restrict__ P2p, const float* __restrict__ ss1,
    float* __restrict__ agg) {
  const int tid = threadIdx.x, lane = tid & 63, w = tid >> 6;
  const int c = lane & 15, q = lane >> 4;
  bf16x8 Bf[16];
  load_W3_frags(W, lane, Bf);
  float bn_[8], sc[8], sh[8];
#pragma unroll
  for (int nt = 0; nt < 8; ++nt) {
    bn_[nt] = b[nt * 16 + c];
    sc[nt]  = ss1[nt * 16 + c];
    sh[nt]  = ss1[128 + nt * 16 + c];
  }
  for (int g0 = blockIdx.x * 64; g0 < N_EDGES; g0 += gridDim.x * 64) {
    const int e0 = g0 + w * 16;
    const int dv = dst[e0 + c];
    const int sv = src[e0 + c];
    const float* er = e_feat + (size_t)(e0 + c) * 64 + q * 8;
    f32x4 a0 = __builtin_nontemporal_load((const f32x4*)er);
    f32x4 a1 = __builtin_nontemporal_load((const f32x4*)(er + 4));
    f32x4 a2 = __builtin_nontemporal_load((const f32x4*)(er + 32));
    f32x4 a3 = __builtin_nontemporal_load((const f32x4*)(er + 36));
    int dIdx[4], sIdx[4];
#pragma unroll
    for (int r = 0; r < 4; ++r) {
      dIdx[r] = __shfl(dv, q * 4 + r, 64);
      sIdx[r] = __shfl(sv, q * 4 + r, 64);
    }
    bf16x8 A0, A1;
#pragma unroll
    for (int j = 0; j < 4; ++j) {
      A0[j] = (__bf16)a0[j]; A0[4 + j] = (__bf16)a1[j];
      A1[j] = (__bf16)a2[j]; A1[4 + j] = (__bf16)a3[j];
    }
    f32x4 acc[8];
#pragma unroll
    for (int nt = 0; nt < 8; ++nt) {
      acc[nt] = (f32x4){0.f, 0.f, 0.f, 0.f};
      acc[nt] = __builtin_amdgcn_mfma_f32_16x16x32_bf16(A0, Bf[nt * 2 + 0], acc[nt], 0, 0, 0);
      acc[nt] = __builtin_amdgcn_mfma_f32_16x16x32_bf16(A1, Bf[nt * 2 + 1], acc[nt], 0, 0, 0);
    }
#pragma unroll
    for (int r = 0; r < 4; ++r) {
      const unsigned* p1r = P1p + (size_t)dIdx[r] * 64 + c;
      const unsigned* p2r = P2p + (size_t)sIdx[r] * 64 + c;
#pragma unroll
      for (int ntp = 0; ntp < 4; ++ntp) {
        unsigned u1 = p1r[ntp * 16];
        unsigned u2 = p2r[ntp * 16];
        float lo = __uint_as_float(u1 << 16) + __uint_as_float(u2 << 16);
        float hi = __uint_as_float(u1 & 0xffff0000u) + __uint_as_float(u2 & 0xffff0000u);
        float hval_lo = acc[ntp][r]     + lo + bn_[ntp];
        float hval_hi = acc[ntp + 4][r] + hi + bn_[ntp + 4];
        float f = hval_lo * sc[ntp] + sh[ntp];
        float g = hval_hi * sc[ntp + 4] + sh[ntp + 4];
        unsafeAtomicAdd(&agg[(size_t)dIdx[r] * 64 + ntp * 16 + c],
                        fast_sigmoid(f) * fast_softplus(g));
      }
    }
  }
}

// Kernel 5: BN2 stats over agg rows (fallback paths only).
__global__ __launch_bounds__(256) void k_agg_stats(const float* __restrict__ agg,
                                                   float* __restrict__ stats2) {
  const int tid = threadIdx.x;
  const int c = tid & 63, w = tid >> 6;
  float s = 0.f, sq = 0.f;
  for (int r = blockIdx.x * 4 + w; r < N_NODES; r += gridDim.x * 4) {
    float v = agg[(size_t)r * 64 + c];
    s += v; sq += v * v;
  }
  __shared__ float ws_[4][64], wq_[4][64];
  ws_[w][c] = s; wq_[w][c] = sq;
  __syncthreads();
  if (tid < 64) {
    unsafeAtomicAdd(&stats2[tid], ws_[0][tid] + ws_[1][tid] + ws_[2][tid] + ws_[3][tid]);
  } else if (tid < 128) {
    int t = tid - 64;
    unsafeAtomicAdd(&stats2[64 + t], wq_[0][t] + wq_[1][t] + wq_[2][t] + wq_[3][t]);
  }
}

__global__ void k_finalize2(const float* __restrict__ stats2,
                            const float* __restrict__ g2,
                            const float* __restrict__ beta2,
                            float* __restrict__ ss2) {
  int t = threadIdx.x;
  if (t < 64) {
    float inv_n = 1.f / (float)N_NODES;
    float mu  = stats2[t] * inv_n;
    float var = stats2[64 + t] * inv_n - mu * mu;
    float sc  = g2[t] * rsqrtf(var + BN_EPS);
    ss2[t] = sc;
    ss2[64 + t] = beta2[t] - mu * sc;
  }
}

// Kernel 7: out = softplus(BN2(agg) + n_feat), float4-vectorized.
__global__ __launch_bounds__(256) void k_output(const float* __restrict__ agg,
                                                const float* __restrict__ n_feat,
                                                const float* __restrict__ ss2,
                                                float* __restrict__ out) {
  int i = blockIdx.x * 256 + threadIdx.x;
  if (i >= N_NODES * 16) return;
  int cb = (i & 15) * 4;
  float4 a = ((const float4*)agg)[i];
  float4 x = ((const float4*)n_feat)[i];
  float4 r;
  r.x = fast_softplus(a.x * ss2[cb + 0] + ss2[64 + cb + 0] + x.x);
  r.y = fast_softplus(a.y * ss2[cb + 1] + ss2[64 + cb + 1] + x.y);
  r.z = fast_softplus(a.z * ss2[cb + 2] + ss2[64 + cb + 2] + x.z);
  r.w = fast_softplus(a.w * ss2[cb + 3] + ss2[64 + cb + 3] + x.w);
  ((float4*)out)[i] = r;
}

extern "C" void kernel_launch(void* const* d_in, const int* in_sizes, int n_in,
                              void* d_out, int out_size, void* d_ws, size_t ws_size,
                              hipStream_t stream) {
  const float* n_feat = (const float*)d_in[0];
  const float* e_feat = (const float*)d_in[1];
  const int*   src    = (const int*)d_in[2];
  const int*   dst    = (const int*)d_in[3];
  const float* W      = (const float*)d_in[4];
  const float* b      = (const float*)d_in[5];
  const float* g1     = (const float*)d_in[6];
  const float* beta1  = (const float*)d_in[7];
  const float* g2     = (const float*)d_in[8];
  const float* beta2  = (const float*)d_in[9];

  unsigned* ws  = (unsigned*)d_ws;
  unsigned* P1p = ws;
  unsigned* P2p = ws + OFF_P2P;
  float* agg    = (float*)(ws + OFF_AGG);
  float* stats1 = (float*)(ws + OFF_STATS1);
  float* ss1    = stats1 + 256;
  float* stats2 = ss1 + 256;
  float* ss2    = stats2 + 128;
  unsigned int* hbuf = ws + OFF_HBUF;
  unsigned* rank   = ws + OFF_RANK;
  unsigned* offs   = ws + OFF_OFFS;
  unsigned* deg    = ws + OFF_DEG;
  unsigned* cursor = ws + OFF_CURS;
  unsigned* bsum   = ws + OFF_BSUM;
  float* out    = (float*)d_out;

  const bool have_hbuf = ws_size >= WS_WORDS_NEEDED * 4;
  const bool have_sort = ws_size >= WS_WORDS_SORTED * 4;

  hipMemsetAsync(stats1, 0, (256 + 256 + 128 + 128) * sizeof(float), stream);

  if (have_sort) {
    hipMemsetAsync(deg, 0, N_NODES * sizeof(unsigned), stream);
    // precompute P tables + fused dst histogram
    k_precompute<<<1024, 256, 0, stream>>>(n_feat, W, P1p, P2p, dst, deg);
    // hierarchical scan
    k_scan1<<<NSCAN_BLOCKS, 256, 0, stream>>>(deg, bsum);
    k_scan2<<<NSCAN_BLOCKS, 256, 0, stream>>>(deg, bsum, offs, cursor);
    k_scatter_ids<<<(N_EDGES + 255) / 256, 256, 0, stream>>>(dst, cursor, rank);
    // sequential-order edge pass, hbuf stores scattered to sorted slots
    k_edge_h<<<2048, 256, 0, stream>>>(e_feat, src, dst, rank, W, b,
                                       P1p, P2p, stats1, hbuf);
    k_finalize1<<<1, 128, 0, stream>>>(stats1, g1, beta1, ss1);
    // pure streaming gather: no indirection, no atomics, fuses BN2 stats
    k_gather_msg<<<2048, 256, 0, stream>>>(hbuf, offs, ss1, agg, stats2);
  } else {
    hipMemsetAsync(agg, 0, (size_t)N_NODES * 64 * sizeof(float), stream);
    k_precompute<<<1024, 256, 0, stream>>>(n_feat, W, P1p, P2p, dst, nullptr);
    if (have_hbuf) {
      k_edge_h<<<2048, 256, 0, stream>>>(e_feat, src, dst, nullptr, W, b,
                                         P1p, P2p, stats1, hbuf);
      k_finalize1<<<1, 128, 0, stream>>>(stats1, g1, beta1, ss1);
      k_msg_scatter<<<2048, 256, 0, stream>>>(hbuf, dst, ss1, agg);
    } else {
      k_edge_h<<<2048, 256, 0, stream>>>(e_feat, src, dst, nullptr, W, b,
                                         P1p, P2p, stats1, nullptr);
      k_finalize1<<<1, 128, 0, stream>>>(stats1, g1, beta1, ss1);
      k_edge_msg<<<2048, 256, 0, stream>>>(e_feat, src, dst, W, b, P1p, P2p, ss1, agg);
    }
    k_agg_stats<<<512, 256, 0, stream>>>(agg, stats2);
  }
  k_finalize2<<<1, 64, 0, stream>>>(stats2, g2, beta2, ss2);
  k_output<<<3125, 256, 0, stream>>>(agg, n_feat, ss2, out);
}

// Round 7
// 659.260 us; speedup vs baseline: 1.2220x; 1.0353x over previous
//
#include <hip/hip_runtime.h>
#include <math.h>

// Problem constants (from reference)
#define N_NODES 50000
#define N_EDGES 800000
#define IN_DIM  192      // 2*O + ED
#define BN_EPS  1e-5f

// Workspace layout (4-byte word offsets):
//   P1p    [N,64]  uint @ 0          packed bf16x2 {chan n, chan n+64} of n_feat@W1^T
//   P2p    [N,64]  uint @ 3,200,000  same for W2^T
//   agg    [N,64]  f32  @ 6,400,000
//   stats1 [256]   f32  @ 9,600,000  (sum[128], sumsq[128])
//   ss1    [256]   f32  @ +256       (scale[128], shift[128])  (fallback path)
//   stats2 [128]   f32  @ +512
//   ss2    [128]   f32  @ +640       (unused in fused path)
//   hbuf   [E,64]  uint @ 9,601,024  packed bf16x2 {filt,core} at SORTED slot
//   rank   [E]     uint @ OFF_RANK   slot index of edge e in dst-sorted order
//   offs   [N+1]   uint @ OFF_OFFS   CSR row offsets per dst node
//   deg    [N]     uint @ OFF_DEG    histogram scratch
//   cursor [N]     uint @ OFF_CURS   scatter cursors (copy of offs)
//   bsum   [256]   uint @ OFF_BSUM   per-block sums for hierarchical scan
#define OFF_P2P    3200000
#define OFF_AGG    6400000
#define OFF_STATS1 9600000
#define OFF_HBUF   9601024
#define WS_WORDS_NEEDED (OFF_HBUF + (size_t)N_EDGES * 64)
#define OFF_RANK   (OFF_HBUF + (size_t)N_EDGES * 64)
#define OFF_OFFS   (OFF_RANK + N_EDGES)
#define OFF_DEG    (OFF_OFFS + N_NODES + 1)
#define OFF_CURS   (OFF_DEG + N_NODES)
#define OFF_BSUM   (OFF_CURS + N_NODES)
#define WS_WORDS_SORTED (OFF_BSUM + 256)

#define NSCAN_BLOCKS 196   // ceil(50000/256)

typedef __bf16 bf16x8 __attribute__((ext_vector_type(8)));
typedef __bf16 bf16x2 __attribute__((ext_vector_type(2)));
typedef float  f32x4  __attribute__((ext_vector_type(4)));

__device__ __forceinline__ unsigned pack_bf16x2(float lo, float hi) {
  union { bf16x2 v; unsigned u; } pk;
  pk.v[0] = (__bf16)lo; pk.v[1] = (__bf16)hi;
  return pk.u;
}
// fast transcendentals (native v_exp/v_log/v_rcp)
__device__ __forceinline__ float fast_sigmoid(float f) {
  return __builtin_amdgcn_rcpf(1.f + __expf(-f));
}
__device__ __forceinline__ float fast_softplus(float g) {
  return fmaxf(g, 0.f) + __logf(1.f + __expf(-fabsf(g)));
}

// ---------------------------------------------------------------------------
// Kernel 1: P1p[n][o] = pack(bf16(n_feat[n]·W[o][0:64]), bf16(n_feat[n]·W[o+64][0:64]))
//           P2p same with k-range 64:128.
// Also (if deg != null) fused histogram of dst for the counting sort.
__global__ __launch_bounds__(256) void k_precompute(
    const float* __restrict__ n_feat, const float* __restrict__ W,
    unsigned* __restrict__ P1p, unsigned* __restrict__ P2p,
    const int* __restrict__ dst, unsigned* __restrict__ deg) {
  const int tid = threadIdx.x;
  if (deg) {
    for (int e = blockIdx.x * 256 + tid; e < N_EDGES; e += gridDim.x * 256)
      atomicAdd(&deg[dst[e]], 1u);
  }
  const int o   = tid & 63;
  const int sel = tid >> 6;                 // 0..3
  const int ch  = o + (sel & 1) * 64;
  const int kb  = (sel & 2) ? 64 : 0;
  float4 wreg[16];
  const float* wrow = W + (size_t)ch * IN_DIM + kb;
#pragma unroll
  for (int i = 0; i < 16; ++i) wreg[i] = *(const float4*)(wrow + i * 4);
  __shared__ float xrow[4][64];
  __shared__ float accbuf[4][4][64];        // [sel][r][o]
  for (int r0 = blockIdx.x * 4; r0 < N_NODES; r0 += gridDim.x * 4) {
    __syncthreads();
    xrow[tid >> 6][tid & 63] = n_feat[(size_t)(r0 + (tid >> 6)) * 64 + (tid & 63)];
    __syncthreads();
    float acc[4] = {0.f, 0.f, 0.f, 0.f};
#pragma unroll
    for (int kk = 0; kk < 16; ++kk) {
      float4 wv = wreg[kk];
#pragma unroll
      for (int r = 0; r < 4; ++r) {
        float4 xv = *(const float4*)&xrow[r][kk * 4];
        acc[r] += wv.x * xv.x + wv.y * xv.y + wv.z * xv.z + wv.w * xv.w;
      }
    }
#pragma unroll
    for (int r = 0; r < 4; ++r) accbuf[sel][r][o] = acc[r];
    __syncthreads();
    // thread (o, sel) packs+writes node row r0+sel
    const size_t rr = (size_t)(r0 + sel) * 64 + o;
    P1p[rr] = pack_bf16x2(accbuf[0][sel][o], accbuf[1][sel][o]);
    P2p[rr] = pack_bf16x2(accbuf[2][sel][o], accbuf[3][sel][o]);
  }
}

// ---------------------------------------------------------------------------
// Hierarchical exclusive scan of deg[N_NODES] -> offs/cursor.
// scan1: per-block (256 elems) sums.
__global__ __launch_bounds__(256) void k_scan1(const unsigned* __restrict__ deg,
                                               unsigned* __restrict__ bsum) {
  const int t = threadIdx.x;
  const int i = blockIdx.x * 256 + t;
  __shared__ unsigned r[256];
  r[t] = (i < N_NODES) ? deg[i] : 0u;
  __syncthreads();
  for (int off = 128; off > 0; off >>= 1) {
    if (t < off) r[t] += r[t + off];
    __syncthreads();
  }
  if (t == 0) bsum[blockIdx.x] = r[0];
}

// scan2: each block redundantly scans bsum[196] (cheap), then local scan.
__global__ __launch_bounds__(256) void k_scan2(const unsigned* __restrict__ deg,
                                               const unsigned* __restrict__ bsum,
                                               unsigned* __restrict__ offs,
                                               unsigned* __restrict__ cursor) {
  const int t = threadIdx.x;
  __shared__ unsigned sb[256];
  sb[t] = (t < NSCAN_BLOCKS) ? bsum[t] : 0u;
  __syncthreads();
  for (int off = 1; off < 256; off <<= 1) {
    unsigned add = (t >= off) ? sb[t - off] : 0u;
    __syncthreads();
    sb[t] += add;
    __syncthreads();
  }
  const unsigned base = (blockIdx.x == 0) ? 0u : sb[blockIdx.x - 1];
  const int i = blockIdx.x * 256 + t;
  const unsigned v = (i < N_NODES) ? deg[i] : 0u;
  __shared__ unsigned sd[256];
  sd[t] = v;
  __syncthreads();
  for (int off = 1; off < 256; off <<= 1) {
    unsigned add = (t >= off) ? sd[t - off] : 0u;
    __syncthreads();
    sd[t] += add;
    __syncthreads();
  }
  const unsigned excl = base + sd[t] - v;
  if (i < N_NODES) { offs[i] = excl; cursor[i] = excl; }
  if (blockIdx.x == 0 && t == 0) offs[N_NODES] = N_EDGES;
}

// rank[e] = slot of edge e in dst-sorted order (stable within a node not
// required; any bijection onto [offs[d], offs[d+1]) works).
__global__ __launch_bounds__(256) void k_scatter_ids(
    const int* __restrict__ dst, unsigned* __restrict__ cursor,
    unsigned* __restrict__ rank) {
  int e = blockIdx.x * 256 + threadIdx.x;
  if (e < N_EDGES) {
    rank[e] = atomicAdd(&cursor[dst[e]], 1u);
  }
}

// ---------------------------------------------------------------------------
// W3 fragment loader shared by edge kernels.
//   D-frag: lane holds D[m=(lane>>4)*4+r][n=nt*16+(lane&15)]
__device__ __forceinline__ void load_W3_frags(const float* __restrict__ W,
                                              int lane, bf16x8* Bf) {
  const int c = lane & 15, q = lane >> 4;
#pragma unroll
  for (int nt = 0; nt < 8; ++nt) {
#pragma unroll
    for (int ks = 0; ks < 2; ++ks) {
      const float* wr = W + (size_t)(nt * 16 + c) * IN_DIM + 128 + ks * 32 + q * 8;
      f32x4 w0 = *(const f32x4*)wr;
      f32x4 w1 = *(const f32x4*)(wr + 4);
      bf16x8 f;
#pragma unroll
      for (int j = 0; j < 4; ++j) { f[j] = (__bf16)w0[j]; f[4 + j] = (__bf16)w1[j]; }
      Bf[nt * 2 + ks] = f;
    }
  }
}

// ---------------------------------------------------------------------------
// Kernel 2: SEQUENTIAL edge order (coalesced e_feat/dst/src/rank streams).
// Wave computes h[16 edges][128 ch]; BN1 stats; hbuf store scattered to
// dst-sorted slot rank[e].
// __launch_bounds__(256,3): 170-reg unified budget fits the ~84 VGPR + 32
// AGPR need with ZERO spill.  (256,4)=128 and (256,6)=85 both spilled
// (FETCH 546/847 MB of scratch traffic vs ~290 real).  3 blocks/CU,
// latency hidden by MLP within the wave.
__global__ __launch_bounds__(256, 3) void k_edge_h(
    const float* __restrict__ e_feat, const int* __restrict__ src,
    const int* __restrict__ dst, const unsigned* __restrict__ rank,
    const float* __restrict__ W, const float* __restrict__ b,
    const unsigned* __restrict__ P1p, const unsigned* __restrict__ P2p,
    float* __restrict__ stats1, unsigned int* __restrict__ hbuf) {
  const int tid = threadIdx.x, lane = tid & 63, w = tid >> 6;
  const int c = lane & 15, q = lane >> 4;
  bf16x8 Bf[16];
  load_W3_frags(W, lane, Bf);
  float bn_[8];
#pragma unroll
  for (int nt = 0; nt < 8; ++nt) bn_[nt] = b[nt * 16 + c];
  float sums[8] = {0, 0, 0, 0, 0, 0, 0, 0};
  float sqs[8]  = {0, 0, 0, 0, 0, 0, 0, 0};
  for (int g0 = blockIdx.x * 64; g0 < N_EDGES; g0 += gridDim.x * 64) {
    const int e0 = g0 + w * 16;
    // one coalesced load per stream, broadcast to r-slots via shfl
    // (lanes 0..15 hold the 16 edges' values)
    const int dv = dst[e0 + c];
    const int sv = src[e0 + c];
    const unsigned rv = rank ? rank[e0 + c] : 0u;
    const float* er = e_feat + (size_t)(e0 + c) * 64 + q * 8;
    f32x4 a0 = __builtin_nontemporal_load((const f32x4*)er);
    f32x4 a1 = __builtin_nontemporal_load((const f32x4*)(er + 4));
    f32x4 a2 = __builtin_nontemporal_load((const f32x4*)(er + 32));
    f32x4 a3 = __builtin_nontemporal_load((const f32x4*)(er + 36));
    int dIdx[4], sIdx[4], tIdx[4];
#pragma unroll
    for (int r = 0; r < 4; ++r) {
      dIdx[r] = __shfl(dv, q * 4 + r, 64);
      sIdx[r] = __shfl(sv, q * 4 + r, 64);
      tIdx[r] = rank ? (int)__shfl((int)rv, q * 4 + r, 64) : (e0 + q * 4 + r);
    }
    bf16x8 A0, A1;
#pragma unroll
    for (int j = 0; j < 4; ++j) {
      A0[j] = (__bf16)a0[j]; A0[4 + j] = (__bf16)a1[j];
      A1[j] = (__bf16)a2[j]; A1[4 + j] = (__bf16)a3[j];
    }
    f32x4 acc[8];
#pragma unroll
    for (int nt = 0; nt < 8; ++nt) {
      acc[nt] = (f32x4){0.f, 0.f, 0.f, 0.f};
      acc[nt] = __builtin_amdgcn_mfma_f32_16x16x32_bf16(A0, Bf[nt * 2 + 0], acc[nt], 0, 0, 0);
      acc[nt] = __builtin_amdgcn_mfma_f32_16x16x32_bf16(A1, Bf[nt * 2 + 1], acc[nt], 0, 0, 0);
    }
    float h[8][4];
#pragma unroll
    for (int r = 0; r < 4; ++r) {
      const unsigned* p1r = P1p + (size_t)dIdx[r] * 64 + c;
      const unsigned* p2r = P2p + (size_t)sIdx[r] * 64 + c;
#pragma unroll
      for (int ntp = 0; ntp < 4; ++ntp) {
        unsigned u1 = p1r[ntp * 16];
        unsigned u2 = p2r[ntp * 16];
        float lo = __uint_as_float(u1 << 16) + __uint_as_float(u2 << 16);
        float hi = __uint_as_float(u1 & 0xffff0000u) + __uint_as_float(u2 & 0xffff0000u);
        h[ntp][r]     = acc[ntp][r]     + lo + bn_[ntp];
        h[ntp + 4][r] = acc[ntp + 4][r] + hi + bn_[ntp + 4];
      }
    }
#pragma unroll
    for (int nt = 0; nt < 8; ++nt)
#pragma unroll
      for (int r = 0; r < 4; ++r) {
        sums[nt] += h[nt][r];
        sqs[nt]  += h[nt][r] * h[nt][r];
      }
    if (hbuf) {
#pragma unroll
      for (int r = 0; r < 4; ++r) {
        unsigned int* hb = hbuf + (size_t)tIdx[r] * 64 + c;
#pragma unroll
        for (int nt = 0; nt < 4; ++nt)
          hb[nt * 16] = pack_bf16x2(h[nt][r], h[nt + 4][r]);
      }
    }
  }
  __shared__ float red[4][256];
#pragma unroll
  for (int nt = 0; nt < 8; ++nt) {
    float s = sums[nt]; s += __shfl_xor(s, 16, 64); s += __shfl_xor(s, 32, 64);
    float qv = sqs[nt]; qv += __shfl_xor(qv, 16, 64); qv += __shfl_xor(qv, 32, 64);
    if (lane < 16) { red[w][nt * 16 + lane] = s; red[w][128 + nt * 16 + lane] = qv; }
  }
  __syncthreads();
  float v = red[0][tid] + red[1][tid] + red[2][tid] + red[3][tid];
  unsafeAtomicAdd(&stats1[tid], v);
}

// Kernel 3 (fallback paths only): fold BN1 into per-channel affine.
__global__ void k_finalize1(const float* __restrict__ stats1,
                            const float* __restrict__ g1,
                            const float* __restrict__ beta1,
                            float* __restrict__ ss1) {
  int t = threadIdx.x;
  if (t < 128) {
    float inv_n = 1.f / (float)N_EDGES;
    float mu  = stats1[t] * inv_n;
    float var = stats1[128 + t] * inv_n - mu * mu;
    float sc  = g1[t] * rsqrtf(var + BN_EPS);
    ss1[t] = sc;
    ss1[128 + t] = beta1[t] - mu * sc;
  }
}

__device__ __forceinline__ float msg_of(unsigned p, float sc_f, float sh_f,
                                        float sc_g, float sh_g) {
  float f = __uint_as_float(p << 16) * sc_f + sh_f;
  float g = __uint_as_float(p & 0xffff0000u) * sc_g + sh_g;
  return fast_sigmoid(f) * fast_softplus(g);
}

// ---------------------------------------------------------------------------
// Kernel 4 (sorted): hbuf is in dst-sorted slot order, so node n owns the
// contiguous slot range [offs[n], offs[n+1]).  Streaming cached reads, BN1
// affine (derived in-block from stats1 -- k_finalize1 dispatch fused away),
// msg=sigmoid*softplus, register-accumulate, single agg write.
// Fuses BN2 stats (no k_agg_stats, no agg memset, zero atomics on agg).
__global__ __launch_bounds__(256) void k_gather_msg(
    const unsigned int* __restrict__ hbuf, const unsigned* __restrict__ offs,
    const float* __restrict__ stats1, const float* __restrict__ g1,
    const float* __restrict__ beta1, float* __restrict__ agg,
    float* __restrict__ stats2) {
  const int tid = threadIdx.x, lane = tid & 63, w = tid >> 6;
  // derive BN1 affine in-block (128 rsqrt, trivial vs a separate dispatch)
  __shared__ float ss1s[256];
  if (tid < 128) {
    const float inv_n = 1.f / (float)N_EDGES;
    float mu  = stats1[tid] * inv_n;
    float var = stats1[128 + tid] * inv_n - mu * mu;
    float sc  = g1[tid] * rsqrtf(var + BN_EPS);
    ss1s[tid] = sc;
    ss1s[128 + tid] = beta1[tid] - mu * sc;
  }
  __syncthreads();
  const float sc_f = ss1s[lane], sc_g = ss1s[64 + lane];
  const float sh_f = ss1s[128 + lane], sh_g = ss1s[192 + lane];
  const int wave_id = blockIdx.x * 4 + w;
  const int n_waves = gridDim.x * 4;
  float ssum = 0.f, ssq = 0.f;
  for (int node = wave_id; node < N_NODES; node += n_waves) {
    const int start = (int)offs[node], end = (int)offs[node + 1];
    float acc = 0.f;
    int j = start;
    for (; j + 8 <= end; j += 8) {
      unsigned p[8];
#pragma unroll
      for (int k = 0; k < 8; ++k) p[k] = hbuf[(size_t)(j + k) * 64 + lane];
#pragma unroll
      for (int k = 0; k < 8; ++k) acc += msg_of(p[k], sc_f, sh_f, sc_g, sh_g);
    }
    for (; j < end; ++j)
      acc += msg_of(hbuf[(size_t)j * 64 + lane], sc_f, sh_f, sc_g, sh_g);
    agg[(size_t)node * 64 + lane] = acc;
    ssum += acc; ssq += acc * acc;
  }
  __shared__ float red[4][64], redq[4][64];
  red[w][lane] = ssum; redq[w][lane] = ssq;
  __syncthreads();
  if (tid < 64) {
    unsafeAtomicAdd(&stats2[tid], red[0][tid] + red[1][tid] + red[2][tid] + red[3][tid]);
  } else if (tid < 128) {
    int t = tid - 64;
    unsafeAtomicAdd(&stats2[64 + t], redq[0][t] + redq[1][t] + redq[2][t] + redq[3][t]);
  }
}

// ---------------------------------------------------------------------------
// Kernel 4 (fallback, atomic): read packed h (edge order), BN1 affine, msg,
// scatter.
__global__ __launch_bounds__(256) void k_msg_scatter(
    const unsigned int* __restrict__ hbuf, const int* __restrict__ dst,
    const float* __restrict__ ss1, float* __restrict__ agg) {
  const int tid = threadIdx.x, lane = tid & 63, w = tid >> 6;
  const float sc_f = ss1[lane], sc_g = ss1[64 + lane];
  const float sh_f = ss1[128 + lane], sh_g = ss1[192 + lane];
  const int wave_id = blockIdx.x * 4 + w;
  const int n_waves = gridDim.x * 4;
  for (int e0 = wave_id * 8; e0 < N_EDGES; e0 += n_waves * 8) {
    unsigned int p[8];
    int d[8];
#pragma unroll
    for (int j = 0; j < 8; ++j) {
      p[j] = hbuf[(size_t)(e0 + j) * 64 + lane];
      d[j] = __builtin_amdgcn_readfirstlane(dst[e0 + j]);
    }
#pragma unroll
    for (int j = 0; j < 8; ++j) {
      unsafeAtomicAdd(&agg[(size_t)d[j] * 64 + lane],
                      msg_of(p[j], sc_f, sh_f, sc_g, sh_g));
    }
  }
}

// Fallback pass 2 (recompute h) if ws_size is too small for hbuf.
__global__ __launch_bounds__(256, 3) void k_edge_msg(
    const float* __restrict__ e_feat, const int* __restrict__ src,
    const int* __restrict__ dst, const float* __restrict__ W,
    const float* __restrict__ b, const unsigned* __restrict__ P1p,
    const unsigned* __restrict__ P2p, const float* __restrict__ ss1,
    float* __restrict__ agg) {
  const int tid = threadIdx.x, lane = tid & 63, w = tid >> 6;
  const int c = lane & 15, q = lane >> 4;
  bf16x8 Bf[16];
  load_W3_frags(W, lane, Bf);
  float bn_[8], sc[8], sh[8];
#pragma unroll
  for (int nt = 0; nt < 8; ++nt) {
    bn_[nt] = b[nt * 16 + c];
    sc[nt]  = ss1[nt * 16 + c];
    sh[nt]  = ss1[128 + nt * 16 + c];
  }
  for (int g0 = blockIdx.x * 64; g0 < N_EDGES; g0 += gridDim.x * 64) {
    const int e0 = g0 + w * 16;
    const int dv = dst[e0 + c];
    const int sv = src[e0 + c];
    const float* er = e_feat + (size_t)(e0 + c) * 64 + q * 8;
    f32x4 a0 = __builtin_nontemporal_load((const f32x4*)er);
    f32x4 a1 = __builtin_nontemporal_load((const f32x4*)(er + 4));
    f32x4 a2 = __builtin_nontemporal_load((const f32x4*)(er + 32));
    f32x4 a3 = __builtin_nontemporal_load((const f32x4*)(er + 36));
    int dIdx[4], sIdx[4];
#pragma unroll
    for (int r = 0; r < 4; ++r) {
      dIdx[r] = __shfl(dv, q * 4 + r, 64);
      sIdx[r] = __shfl(sv, q * 4 + r, 64);
    }
    bf16x8 A0, A1;
#pragma unroll
    for (int j = 0; j < 4; ++j) {
      A0[j] = (__bf16)a0[j]; A0[4 + j] = (__bf16)a1[j];
      A1[j] = (__bf16)a2[j]; A1[4 + j] = (__bf16)a3[j];
    }
    f32x4 acc[8];
#pragma unroll
    for (int nt = 0; nt < 8; ++nt) {
      acc[nt] = (f32x4){0.f, 0.f, 0.f, 0.f};
      acc[nt] = __builtin_amdgcn_mfma_f32_16x16x32_bf16(A0, Bf[nt * 2 + 0], acc[nt], 0, 0, 0);
      acc[nt] = __builtin_amdgcn_mfma_f32_16x16x32_bf16(A1, Bf[nt * 2 + 1], acc[nt], 0, 0, 0);
    }
#pragma unroll
    for (int r = 0; r < 4; ++r) {
      const unsigned* p1r = P1p + (size_t)dIdx[r] * 64 + c;
      const unsigned* p2r = P2p + (size_t)sIdx[r] * 64 + c;
#pragma unroll
      for (int ntp = 0; ntp < 4; ++ntp) {
        unsigned u1 = p1r[ntp * 16];
        unsigned u2 = p2r[ntp * 16];
        float lo = __uint_as_float(u1 << 16) + __uint_as_float(u2 << 16);
        float hi = __uint_as_float(u1 & 0xffff0000u) + __uint_as_float(u2 & 0xffff0000u);
        float hval_lo = acc[ntp][r]     + lo + bn_[ntp];
        float hval_hi = acc[ntp + 4][r] + hi + bn_[ntp + 4];
        float f = hval_lo * sc[ntp] + sh[ntp];
        float g = hval_hi * sc[ntp + 4] + sh[ntp + 4];
        unsafeAtomicAdd(&agg[(size_t)dIdx[r] * 64 + ntp * 16 + c],
                        fast_sigmoid(f) * fast_softplus(g));
      }
    }
  }
}

// Kernel 5: BN2 stats over agg rows (fallback paths only).
__global__ __launch_bounds__(256) void k_agg_stats(const float* __restrict__ agg,
                                                   float* __restrict__ stats2) {
  const int tid = threadIdx.x;
  const int c = tid & 63, w = tid >> 6;
  float s = 0.f, sq = 0.f;
  for (int r = blockIdx.x * 4 + w; r < N_NODES; r += gridDim.x * 4) {
    float v = agg[(size_t)r * 64 + c];
    s += v; sq += v * v;
  }
  __shared__ float ws_[4][64], wq_[4][64];
  ws_[w][c] = s; wq_[w][c] = sq;
  __syncthreads();
  if (tid < 64) {
    unsafeAtomicAdd(&stats2[tid], ws_[0][tid] + ws_[1][tid] + ws_[2][tid] + ws_[3][tid]);
  } else if (tid < 128) {
    int t = tid - 64;
    unsafeAtomicAdd(&stats2[64 + t], wq_[0][t] + wq_[1][t] + wq_[2][t] + wq_[3][t]);
  }
}

// Kernel 7: out = softplus(BN2(agg) + n_feat), float4-vectorized.
// BN2 affine derived in-block from stats2 (k_finalize2 dispatch fused away).
__global__ __launch_bounds__(256) void k_output(const float* __restrict__ agg,
                                                const float* __restrict__ n_feat,
                                                const float* __restrict__ stats2,
                                                const float* __restrict__ g2,
                                                const float* __restrict__ beta2,
                                                float* __restrict__ out) {
  const int tid = threadIdx.x;
  __shared__ float ss2s[128];
  if (tid < 64) {
    const float inv_n = 1.f / (float)N_NODES;
    float mu  = stats2[tid] * inv_n;
    float var = stats2[64 + tid] * inv_n - mu * mu;
    float sc  = g2[tid] * rsqrtf(var + BN_EPS);
    ss2s[tid] = sc;
    ss2s[64 + tid] = beta2[tid] - mu * sc;
  }
  __syncthreads();
  int i = blockIdx.x * 256 + tid;
  if (i >= N_NODES * 16) return;
  int cb = (i & 15) * 4;
  float4 a = ((const float4*)agg)[i];
  float4 x = ((const float4*)n_feat)[i];
  float4 r;
  r.x = fast_softplus(a.x * ss2s[cb + 0] + ss2s[64 + cb + 0] + x.x);
  r.y = fast_softplus(a.y * ss2s[cb + 1] + ss2s[64 + cb + 1] + x.y);
  r.z = fast_softplus(a.z * ss2s[cb + 2] + ss2s[64 + cb + 2] + x.z);
  r.w = fast_softplus(a.w * ss2s[cb + 3] + ss2s[64 + cb + 3] + x.w);
  ((float4*)out)[i] = r;
}

extern "C" void kernel_launch(void* const* d_in, const int* in_sizes, int n_in,
                              void* d_out, int out_size, void* d_ws, size_t ws_size,
                              hipStream_t stream) {
  const float* n_feat = (const float*)d_in[0];
  const float* e_feat = (const float*)d_in[1];
  const int*   src    = (const int*)d_in[2];
  const int*   dst    = (const int*)d_in[3];
  const float* W      = (const float*)d_in[4];
  const float* b      = (const float*)d_in[5];
  const float* g1     = (const float*)d_in[6];
  const float* beta1  = (const float*)d_in[7];
  const float* g2     = (const float*)d_in[8];
  const float* beta2  = (const float*)d_in[9];

  unsigned* ws  = (unsigned*)d_ws;
  unsigned* P1p = ws;
  unsigned* P2p = ws + OFF_P2P;
  float* agg    = (float*)(ws + OFF_AGG);
  float* stats1 = (float*)(ws + OFF_STATS1);
  float* ss1    = stats1 + 256;
  float* stats2 = ss1 + 256;
  unsigned int* hbuf = ws + OFF_HBUF;
  unsigned* rank   = ws + OFF_RANK;
  unsigned* offs   = ws + OFF_OFFS;
  unsigned* deg    = ws + OFF_DEG;
  unsigned* cursor = ws + OFF_CURS;
  unsigned* bsum   = ws + OFF_BSUM;
  float* out    = (float*)d_out;

  const bool have_hbuf = ws_size >= WS_WORDS_NEEDED * 4;
  const bool have_sort = ws_size >= WS_WORDS_SORTED * 4;

  hipMemsetAsync(stats1, 0, (256 + 256 + 128 + 128) * sizeof(float), stream);

  if (have_sort) {
    hipMemsetAsync(deg, 0, N_NODES * sizeof(unsigned), stream);
    // precompute P tables + fused dst histogram
    k_precompute<<<1024, 256, 0, stream>>>(n_feat, W, P1p, P2p, dst, deg);
    // hierarchical scan
    k_scan1<<<NSCAN_BLOCKS, 256, 0, stream>>>(deg, bsum);
    k_scan2<<<NSCAN_BLOCKS, 256, 0, stream>>>(deg, bsum, offs, cursor);
    k_scatter_ids<<<(N_EDGES + 255) / 256, 256, 0, stream>>>(dst, cursor, rank);
    // sequential-order edge pass, hbuf stores scattered to sorted slots
    k_edge_h<<<2048, 256, 0, stream>>>(e_feat, src, dst, rank, W, b,
                                       P1p, P2p, stats1, hbuf);
    // streaming gather: BN1 affine derived in-block, no atomics on agg,
    // fuses BN2 stats
    k_gather_msg<<<4096, 256, 0, stream>>>(hbuf, offs, stats1, g1, beta1,
                                           agg, stats2);
  } else {
    hipMemsetAsync(agg, 0, (size_t)N_NODES * 64 * sizeof(float), stream);
    k_precompute<<<1024, 256, 0, stream>>>(n_feat, W, P1p, P2p, dst, nullptr);
    if (have_hbuf) {
      k_edge_h<<<2048, 256, 0, stream>>>(e_feat, src, dst, nullptr, W, b,
                                         P1p, P2p, stats1, hbuf);
      k_finalize1<<<1, 128, 0, stream>>>(stats1, g1, beta1, ss1);
      k_msg_scatter<<<2048, 256, 0, stream>>>(hbuf, dst, ss1, agg);
    } else {
      k_edge_h<<<2048, 256, 0, stream>>>(e_feat, src, dst, nullptr, W, b,
                                         P1p, P2p, stats1, nullptr);
      k_finalize1<<<1, 128, 0, stream>>>(stats1, g1, beta1, ss1);
      k_edge_msg<<<2048, 256, 0, stream>>>(e_feat, src, dst, W, b, P1p, P2p, ss1, agg);
    }
    k_agg_stats<<<512, 256, 0, stream>>>(agg, stats2);
  }
  k_output<<<3125, 256, 0, stream>>>(agg, n_feat, stats2, g2, beta2, out);
}